// Round 1
// baseline (4829.633 us; speedup 1.0000x reference)
//
#include <hip/hip_runtime.h>

#define HH 768
#define WW 768
#define CH 3
#define KS 24
#define HC 745   // 768-24+1
#define WC 745
#define NP 256   // patches (16x16)
#define XH 384
#define XW 384

#define TROWS 32
#define TCOLS 64
#define PPB 4
#define LDW 88   // LDS tile row pitch (needs 87, pad to 88 for alignment)
#define LDH 55   // 32 + 23
#define NTX 12   // ceil(745/64)
#define NTY 24   // ceil(745/32)
#define NTILES (NTX*NTY)   // 288

// -------------------- small prep kernels --------------------

// per-pixel channel sums of y_dec and y_dec^2
__global__ void k_colsum(const float* __restrict__ y, float* __restrict__ ksum,
                         float* __restrict__ ksum2) {
    int idx = blockIdx.x * 256 + threadIdx.x;
    if (idx >= HH * WW) return;
    float a = y[idx], b = y[idx + HH * WW], c = y[idx + 2 * HH * WW];
    ksum[idx]  = a + b + c;
    ksum2[idx] = a * a + b * b + c * c;
}

// horizontal 24-wide box sum
__global__ void k_hsum(const float* __restrict__ ksum, const float* __restrict__ ksum2,
                       float* __restrict__ h1, float* __restrict__ h2) {
    int idx = blockIdx.x * 256 + threadIdx.x;   // h*WC + w, h<768, w<745
    if (idx >= HH * WC) return;
    int h = idx / WC, w = idx % WC;
    const float* r  = ksum  + h * WW + w;
    const float* r2 = ksum2 + h * WW + w;
    float s = 0.f, s2 = 0.f;
    #pragma unroll
    for (int j = 0; j < KS; j++) { s += r[j]; s2 += r2[j]; }
    h1[idx] = s; h2[idx] = s2;
}

// vertical 24-tall box sum + finalize S1 map and 1/den_y map
__global__ void k_vsum(const float* __restrict__ h1, const float* __restrict__ h2,
                       float* __restrict__ s1map, float* __restrict__ invd) {
    int idx = blockIdx.x * 256 + threadIdx.x;   // r*WC + w, r<745
    if (idx >= HC * WC) return;
    int r = idx / WC, w = idx % WC;
    float s = 0.f, s2 = 0.f;
    #pragma unroll
    for (int i = 0; i < KS; i++) { s += h1[(r + i) * WC + w]; s2 += h2[(r + i) * WC + w]; }
    s1map[idx] = s;
    float d2 = s2 - s * s * (1.0f / 576.0f);   // n = K*K = 576 per reference
    invd[idx] = rsqrtf(fmaxf(d2, 1e-20f));
}

// per-patch mean of x (over C*K*K = 1728 elements)
__global__ void k_meanx(const float* __restrict__ x, float* __restrict__ mx) {
    int p = blockIdx.x;
    int pr = p >> 4, pc = p & 15;
    float s = 0.f;
    for (int e = threadIdx.x; e < CH * KS * KS; e += 256) {
        int c = e / (KS * KS); int rem = e % (KS * KS);
        int i = rem / KS, j = rem % KS;
        s += x[(c * XH + pr * KS + i) * XW + pc * KS + j];
    }
    __shared__ float red[256];
    red[threadIdx.x] = s; __syncthreads();
    for (int st = 128; st > 0; st >>= 1) {
        if (threadIdx.x < st) red[threadIdx.x] += red[threadIdx.x + st];
        __syncthreads();
    }
    if (threadIdx.x == 0) mx[p] = red[0] * (1.0f / 1728.0f);
}

// -------------------- main correlation + argmax kernel --------------------

__global__ __launch_bounds__(256) void k_corr(
    const float* __restrict__ ydec, const float* __restrict__ xdec,
    const float* __restrict__ s1map, const float* __restrict__ invd,
    const float* __restrict__ mx, float* __restrict__ pscore, int* __restrict__ pidx) {
    __shared__ float ylds[LDH * LDW];          // 19360 B; reused for reduction
    float* scoreL = ylds;                      // [PPB*256] floats (4 KB)
    int*   idxL   = (int*)(ylds + PPB * 256);  // [PPB*256] ints  (4 KB)

    const int tid = threadIdx.x;
    const int ty = tid >> 3;                   // 0..31 tile row
    const int tg = tid & 7;                    // col group (8 cols each)
    const int row0 = blockIdx.y * TROWS;
    const int col0 = blockIdx.x * TCOLS;

    float acc[PPB][8];
    #pragma unroll
    for (int p = 0; p < PPB; p++)
        #pragma unroll
        for (int t = 0; t < 8; t++) acc[p][t] = 0.f;

    #pragma unroll 1
    for (int c = 0; c < CH; c++) {
        __syncthreads();
        // stage y channel tile: rows row0..row0+54, cols col0..col0+87 (zero-pad OOB)
        const float* yc = ydec + c * HH * WW;
        for (int e = tid; e < LDH * (LDW / 4); e += 256) {   // 1210 float4s
            int rr = e / (LDW / 4);
            int c4 = (e % (LDW / 4)) * 4;
            int gr = row0 + rr, gc = col0 + c4;
            float4 v;
            if (gr < HH && gc + 3 < WW) {
                v = *(const float4*)(yc + gr * WW + gc);
            } else {
                v.x = (gr < HH && gc + 0 < WW) ? yc[gr * WW + gc + 0] : 0.f;
                v.y = (gr < HH && gc + 1 < WW) ? yc[gr * WW + gc + 1] : 0.f;
                v.z = (gr < HH && gc + 2 < WW) ? yc[gr * WW + gc + 2] : 0.f;
                v.w = (gr < HH && gc + 3 < WW) ? yc[gr * WW + gc + 3] : 0.f;
            }
            *(float4*)(ylds + rr * LDW + c4) = v;
        }
        __syncthreads();

        #pragma unroll 1
        for (int i = 0; i < KS; i++) {
            // sliding-window register cache: 32 floats cover cols [tg*8 .. tg*8+31]
            float yv[32];
            const float* ybase = ylds + (ty + i) * LDW + tg * 8;
            #pragma unroll
            for (int k = 0; k < 8; k++) {
                float4 v = *(const float4*)(ybase + 4 * k);
                yv[4 * k + 0] = v.x; yv[4 * k + 1] = v.y;
                yv[4 * k + 2] = v.z; yv[4 * k + 3] = v.w;
            }
            #pragma unroll
            for (int p = 0; p < PPB; p++) {
                int pat = blockIdx.z * PPB + p;
                int pr = pat >> 4, pc = pat & 15;
                // wave-uniform address -> scalar loads (SGPR operands for FMA)
                const float* xr = xdec + (c * XH + pr * KS + i) * XW + pc * KS;
                #pragma unroll
                for (int j = 0; j < KS; j++) {
                    float pv = xr[j];
                    #pragma unroll
                    for (int t = 0; t < 8; t++)
                        acc[p][t] = fmaf(yv[j + t], pv, acc[p][t]);
                }
            }
        }
    }

    // -------- scoring + per-block argmax --------
    const int row = row0 + ty;
    __syncthreads();   // done reading ylds as y tile; reuse as reduction space
    #pragma unroll
    for (int p = 0; p < PPB; p++) {
        float mxp = mx[blockIdx.z * PPB + p];
        float bs = -1e30f; int bi = 0x7FFFFFFF;
        if (row < HC) {
            #pragma unroll
            for (int t = 0; t < 8; t++) {
                int col = col0 + tg * 8 + t;
                if (col < WC) {
                    int pos = row * WC + col;
                    float sc = (acc[p][t] - mxp * s1map[pos]) * invd[pos];
                    if (sc > bs) { bs = sc; bi = pos; }   // ascending col: keeps first
                }
            }
        }
        scoreL[p * 256 + tid] = bs;
        idxL[p * 256 + tid]   = bi;
    }
    __syncthreads();

    // wave w reduces patch w (PPB==4 waves)
    {
        int wid = tid >> 6, lane = tid & 63;
        int p = wid;
        float bs = -1e30f; int bi = 0x7FFFFFFF;
        for (int k = lane; k < 256; k += 64) {
            float s = scoreL[p * 256 + k]; int ii = idxL[p * 256 + k];
            if (s > bs || (s == bs && ii < bi)) { bs = s; bi = ii; }
        }
        #pragma unroll
        for (int off = 32; off > 0; off >>= 1) {
            float os = __shfl_down(bs, off);
            int   oi = __shfl_down(bi, off);
            if (os > bs || (os == bs && oi < bi)) { bs = os; bi = oi; }
        }
        if (lane == 0) {
            int tileIdx = blockIdx.y * NTX + blockIdx.x;     // 0..287
            int pat = blockIdx.z * PPB + p;
            pscore[pat * NTILES + tileIdx] = bs;
            pidx[pat * NTILES + tileIdx]   = bi;
        }
    }
}

// -------------------- final reduce + gather --------------------

__global__ void k_final(const float* __restrict__ pscore, const int* __restrict__ pidx,
                        const float* __restrict__ yfull, float* __restrict__ out) {
    int p = blockIdx.x, tid = threadIdx.x;
    __shared__ float sS[256];
    __shared__ int   sI[256];
    float bs = -1e30f; int bi = 0x7FFFFFFF;
    for (int k = tid; k < NTILES; k += 256) {
        float s = pscore[p * NTILES + k]; int ii = pidx[p * NTILES + k];
        if (s > bs || (s == bs && ii < bi)) { bs = s; bi = ii; }
    }
    sS[tid] = bs; sI[tid] = bi; __syncthreads();
    for (int st = 128; st > 0; st >>= 1) {
        if (tid < st) {
            if (sS[tid + st] > sS[tid] || (sS[tid + st] == sS[tid] && sI[tid + st] < sI[tid])) {
                sS[tid] = sS[tid + st]; sI[tid] = sI[tid + st];
            }
        }
        __syncthreads();
    }
    int best = sI[0];
    int row = best / WC, col = best % WC;
    for (int e = tid; e < CH * KS * KS; e += 256) {
        int c = e / (KS * KS); int rem = e % (KS * KS);
        int i = rem / KS, j = rem % KS;
        out[p * CH * KS * KS + e] = yfull[(c * HH + row + i) * WW + col + j];
    }
}

// -------------------- launch --------------------

extern "C" void kernel_launch(void* const* d_in, const int* in_sizes, int n_in,
                              void* d_out, int out_size, void* d_ws, size_t ws_size,
                              hipStream_t stream) {
    const float* xdec = (const float*)d_in[0];   // (1,3,384,384)
    const float* ydec = (const float*)d_in[1];   // (1,3,768,768)
    const float* y    = (const float*)d_in[2];   // (1,3,768,768)
    float* out = (float*)d_out;                  // (256,3,24,24)

    float* ws = (float*)d_ws;
    // layout (floats):
    float* ksum  = ws + 0;          // 589824
    float* ksum2 = ws + 589824;     // 589824
    float* h1    = ws + 1179648;    // 572160
    float* h2    = ws + 1751808;    // 572160
    float* s1map = ws + 2323968;    // 555025
    float* invd  = ws + 2878993;    // 555025
    float* mx    = ws + 3434018;    // 256
    // pscore/pidx alias the ksum region (fully consumed before k_corr runs)
    float* pscore = ws;                         // 73728
    int*   pidx   = (int*)(ws + NP * NTILES);   // 73728

    k_colsum<<<(HH * WW + 255) / 256, 256, 0, stream>>>(ydec, ksum, ksum2);
    k_hsum<<<(HH * WC + 255) / 256, 256, 0, stream>>>(ksum, ksum2, h1, h2);
    k_vsum<<<(HC * WC + 255) / 256, 256, 0, stream>>>(h1, h2, s1map, invd);
    k_meanx<<<NP, 256, 0, stream>>>(xdec, mx);

    dim3 grid(NTX, NTY, NP / PPB);
    k_corr<<<grid, 256, 0, stream>>>(ydec, xdec, s1map, invd, mx, pscore, pidx);

    k_final<<<NP, 256, 0, stream>>>(pscore, pidx, y, out);
}

// Round 2
// 4774.110 us; speedup vs baseline: 1.0116x; 1.0116x over previous
//
#include <hip/hip_runtime.h>

#define HH 768
#define WW 768
#define CH 3
#define KS 24
#define HC 745   // 768-24+1
#define WC 745
#define NP 256   // patches (16x16)
#define XH 384
#define XW 384

#define TROWS 32
#define TCOLS 64
#define PPB 4
#define LDW 100  // LDS tile row pitch: 100 ≡ 4 (mod 32) -> row adds +1 bank-group; 16B aligned
#define LDW4 (LDW/4)
#define LDH 55   // 32 + 23
#define NTX 12   // ceil(745/64)
#define NTY 24   // ceil(745/32)
#define NTILES (NTX*NTY)   // 288

// -------------------- small prep kernels --------------------

// per-pixel channel sums of y_dec and y_dec^2
__global__ void k_colsum(const float* __restrict__ y, float* __restrict__ ksum,
                         float* __restrict__ ksum2) {
    int idx = blockIdx.x * 256 + threadIdx.x;
    if (idx >= HH * WW) return;
    float a = y[idx], b = y[idx + HH * WW], c = y[idx + 2 * HH * WW];
    ksum[idx]  = a + b + c;
    ksum2[idx] = a * a + b * b + c * c;
}

// horizontal 24-wide box sum
__global__ void k_hsum(const float* __restrict__ ksum, const float* __restrict__ ksum2,
                       float* __restrict__ h1, float* __restrict__ h2) {
    int idx = blockIdx.x * 256 + threadIdx.x;   // h*WC + w, h<768, w<745
    if (idx >= HH * WC) return;
    int h = idx / WC, w = idx % WC;
    const float* r  = ksum  + h * WW + w;
    const float* r2 = ksum2 + h * WW + w;
    float s = 0.f, s2 = 0.f;
    #pragma unroll
    for (int j = 0; j < KS; j++) { s += r[j]; s2 += r2[j]; }
    h1[idx] = s; h2[idx] = s2;
}

// vertical 24-tall box sum + finalize S1 map and 1/den_y map
__global__ void k_vsum(const float* __restrict__ h1, const float* __restrict__ h2,
                       float* __restrict__ s1map, float* __restrict__ invd) {
    int idx = blockIdx.x * 256 + threadIdx.x;   // r*WC + w, r<745
    if (idx >= HC * WC) return;
    int r = idx / WC, w = idx % WC;
    float s = 0.f, s2 = 0.f;
    #pragma unroll
    for (int i = 0; i < KS; i++) { s += h1[(r + i) * WC + w]; s2 += h2[(r + i) * WC + w]; }
    s1map[idx] = s;
    float d2 = s2 - s * s * (1.0f / 576.0f);   // n = K*K = 576 per reference
    invd[idx] = rsqrtf(fmaxf(d2, 1e-20f));
}

// per-patch mean of x (over C*K*K = 1728 elements)
__global__ void k_meanx(const float* __restrict__ x, float* __restrict__ mx) {
    int p = blockIdx.x;
    int pr = p >> 4, pc = p & 15;
    float s = 0.f;
    for (int e = threadIdx.x; e < CH * KS * KS; e += 256) {
        int c = e / (KS * KS); int rem = e % (KS * KS);
        int i = rem / KS, j = rem % KS;
        s += x[(c * XH + pr * KS + i) * XW + pc * KS + j];
    }
    __shared__ float red[256];
    red[threadIdx.x] = s; __syncthreads();
    for (int st = 128; st > 0; st >>= 1) {
        if (threadIdx.x < st) red[threadIdx.x] += red[threadIdx.x + st];
        __syncthreads();
    }
    if (threadIdx.x == 0) mx[p] = red[0] * (1.0f / 1728.0f);
}

// -------------------- main correlation + argmax kernel --------------------

__global__ __launch_bounds__(256) void k_corr(
    const float* __restrict__ ydec, const float* __restrict__ xdec,
    const float* __restrict__ s1map, const float* __restrict__ invd,
    const float* __restrict__ mx, float* __restrict__ pscore, int* __restrict__ pidx) {
    __shared__ float ylds[LDH * LDW];          // 22000 B; reused for reduction
    float* scoreL = ylds;                      // [PPB*256] floats (4 KB)
    int*   idxL   = (int*)(ylds + PPB * 256);  // [PPB*256] ints  (4 KB)

    const int tid  = threadIdx.x;
    const int wave = tid >> 6;
    const int lane = tid & 63;
    // Bank-conflict-free mapping: lane's LDS bank-group for the b128 reads is
    // ((ty+i)*25 + 2*tg + k) mod 8 = (lane&7) + 2*(lane>>3) + const (mod 8)
    // -> every consecutive-8-lane phase covers all 8 four-bank groups once.
    const int tyw = lane & 7;                  // row within wave's 8-row band
    const int tg  = lane >> 3;                 // col group (8 cols each)
    const int ty  = wave * 8 + tyw;            // 0..31 tile row
    const int row0 = blockIdx.y * TROWS;
    const int col0 = blockIdx.x * TCOLS;

    float acc[PPB][8];
    #pragma unroll
    for (int p = 0; p < PPB; p++)
        #pragma unroll
        for (int t = 0; t < 8; t++) acc[p][t] = 0.f;

    #pragma unroll 1
    for (int c = 0; c < CH; c++) {
        __syncthreads();
        // stage y channel tile: rows row0..row0+54, cols col0..col0+99 (zero-pad OOB)
        const float* yc = ydec + c * HH * WW;
        for (int e = tid; e < LDH * LDW4; e += 256) {   // 1375 float4s
            int rr = e / LDW4;
            int c4 = (e % LDW4) * 4;
            int gr = row0 + rr, gc = col0 + c4;
            float4 v;
            if (gr < HH && gc + 3 < WW) {
                v = *(const float4*)(yc + gr * WW + gc);
            } else {
                v.x = (gr < HH && gc + 0 < WW) ? yc[gr * WW + gc + 0] : 0.f;
                v.y = (gr < HH && gc + 1 < WW) ? yc[gr * WW + gc + 1] : 0.f;
                v.z = (gr < HH && gc + 2 < WW) ? yc[gr * WW + gc + 2] : 0.f;
                v.w = (gr < HH && gc + 3 < WW) ? yc[gr * WW + gc + 3] : 0.f;
            }
            *(float4*)(ylds + rr * LDW + c4) = v;
        }
        __syncthreads();

        #pragma unroll 1
        for (int i = 0; i < KS; i++) {
            // sliding-window register cache: 32 floats cover cols [tg*8 .. tg*8+31]
            float yv[32];
            const float* ybase = ylds + (ty + i) * LDW + tg * 8;
            #pragma unroll
            for (int k = 0; k < 8; k++) {
                float4 v = *(const float4*)(ybase + 4 * k);
                yv[4 * k + 0] = v.x; yv[4 * k + 1] = v.y;
                yv[4 * k + 2] = v.z; yv[4 * k + 3] = v.w;
            }
            #pragma unroll
            for (int p = 0; p < PPB; p++) {
                int pat = blockIdx.z * PPB + p;
                int pr = pat >> 4, pc = pat & 15;
                // wave-uniform address -> scalar loads (SGPR operands for FMA)
                const float* xr = xdec + (c * XH + pr * KS + i) * XW + pc * KS;
                #pragma unroll
                for (int j = 0; j < KS; j++) {
                    float pv = xr[j];
                    #pragma unroll
                    for (int t = 0; t < 8; t++)
                        acc[p][t] = fmaf(yv[j + t], pv, acc[p][t]);
                }
            }
        }
    }

    // -------- scoring + per-block argmax --------
    const int row = row0 + ty;
    __syncthreads();   // done reading ylds as y tile; reuse as reduction space
    #pragma unroll
    for (int p = 0; p < PPB; p++) {
        float mxp = mx[blockIdx.z * PPB + p];
        float bs = -1e30f; int bi = 0x7FFFFFFF;
        if (row < HC) {
            #pragma unroll
            for (int t = 0; t < 8; t++) {
                int col = col0 + tg * 8 + t;
                if (col < WC) {
                    int pos = row * WC + col;
                    float sc = (acc[p][t] - mxp * s1map[pos]) * invd[pos];
                    if (sc > bs) { bs = sc; bi = pos; }   // ascending col: keeps first
                }
            }
        }
        scoreL[p * 256 + tid] = bs;
        idxL[p * 256 + tid]   = bi;
    }
    __syncthreads();

    // wave w reduces patch w (PPB==4 waves)
    {
        int wid = tid >> 6, lane2 = tid & 63;
        int p = wid;
        float bs = -1e30f; int bi = 0x7FFFFFFF;
        for (int k = lane2; k < 256; k += 64) {
            float s = scoreL[p * 256 + k]; int ii = idxL[p * 256 + k];
            if (s > bs || (s == bs && ii < bi)) { bs = s; bi = ii; }
        }
        #pragma unroll
        for (int off = 32; off > 0; off >>= 1) {
            float os = __shfl_down(bs, off);
            int   oi = __shfl_down(bi, off);
            if (os > bs || (os == bs && oi < bi)) { bs = os; bi = oi; }
        }
        if (lane2 == 0) {
            int tileIdx = blockIdx.y * NTX + blockIdx.x;     // 0..287
            int pat = blockIdx.z * PPB + p;
            pscore[pat * NTILES + tileIdx] = bs;
            pidx[pat * NTILES + tileIdx]   = bi;
        }
    }
}

// -------------------- final reduce + gather --------------------

__global__ void k_final(const float* __restrict__ pscore, const int* __restrict__ pidx,
                        const float* __restrict__ yfull, float* __restrict__ out) {
    int p = blockIdx.x, tid = threadIdx.x;
    __shared__ float sS[256];
    __shared__ int   sI[256];
    float bs = -1e30f; int bi = 0x7FFFFFFF;
    for (int k = tid; k < NTILES; k += 256) {
        float s = pscore[p * NTILES + k]; int ii = pidx[p * NTILES + k];
        if (s > bs || (s == bs && ii < bi)) { bs = s; bi = ii; }
    }
    sS[tid] = bs; sI[tid] = bi; __syncthreads();
    for (int st = 128; st > 0; st >>= 1) {
        if (tid < st) {
            if (sS[tid + st] > sS[tid] || (sS[tid + st] == sS[tid] && sI[tid + st] < sI[tid])) {
                sS[tid] = sS[tid + st]; sI[tid] = sI[tid + st];
            }
        }
        __syncthreads();
    }
    int best = sI[0];
    int row = best / WC, col = best % WC;
    for (int e = tid; e < CH * KS * KS; e += 256) {
        int c = e / (KS * KS); int rem = e % (KS * KS);
        int i = rem / KS, j = rem % KS;
        out[p * CH * KS * KS + e] = yfull[(c * HH + row + i) * WW + col + j];
    }
}

// -------------------- launch --------------------

extern "C" void kernel_launch(void* const* d_in, const int* in_sizes, int n_in,
                              void* d_out, int out_size, void* d_ws, size_t ws_size,
                              hipStream_t stream) {
    const float* xdec = (const float*)d_in[0];   // (1,3,384,384)
    const float* ydec = (const float*)d_in[1];   // (1,3,768,768)
    const float* y    = (const float*)d_in[2];   // (1,3,768,768)
    float* out = (float*)d_out;                  // (256,3,24,24)

    float* ws = (float*)d_ws;
    // layout (floats):
    float* ksum  = ws + 0;          // 589824
    float* ksum2 = ws + 589824;     // 589824
    float* h1    = ws + 1179648;    // 572160
    float* h2    = ws + 1751808;    // 572160
    float* s1map = ws + 2323968;    // 555025
    float* invd  = ws + 2878993;    // 555025
    float* mx    = ws + 3434018;    // 256
    // pscore/pidx alias the ksum region (fully consumed before k_corr runs)
    float* pscore = ws;                         // 73728
    int*   pidx   = (int*)(ws + NP * NTILES);   // 73728

    k_colsum<<<(HH * WW + 255) / 256, 256, 0, stream>>>(ydec, ksum, ksum2);
    k_hsum<<<(HH * WC + 255) / 256, 256, 0, stream>>>(ksum, ksum2, h1, h2);
    k_vsum<<<(HC * WC + 255) / 256, 256, 0, stream>>>(h1, h2, s1map, invd);
    k_meanx<<<NP, 256, 0, stream>>>(xdec, mx);

    dim3 grid(NTX, NTY, NP / PPB);
    k_corr<<<grid, 256, 0, stream>>>(ydec, xdec, s1map, invd, mx, pscore, pidx);

    k_final<<<NP, 256, 0, stream>>>(pscore, pidx, y, out);
}

// Round 3
// 1876.004 us; speedup vs baseline: 2.5744x; 2.5448x over previous
//
#include <hip/hip_runtime.h>

typedef __bf16 bf16x8 __attribute__((ext_vector_type(8)));
typedef float  v4f    __attribute__((ext_vector_type(4)));
typedef unsigned short ushort_t;

#define HH 768
#define WW 768
#define CH 3
#define KS 24
#define HC 745   // 768-24+1
#define WC 745
#define NP 256   // patches (16x16)
#define XH 384
#define XW 384

// k_corr blocking: block tile = 128 positions (4 rows x 32 cols) x 256 patches
#define NBX 24            // ceil(745/32)
#define NBY 187           // ceil(745/4)
#define NBLK (NBX*NBY)    // 4488
#define BROWS 4
#define BCOLS 32
#define NSTEP 54          // K=1728 in 32-wide slices
#define APITCH 40         // ushorts per A_lds row: 32 data + 8 pad (80 B, 16B-mult, odd/16 -> conflict-free)
#define BPITCH 40
#define NCAND 8

// -------------------- prep kernels (unchanged from R2) --------------------

__global__ void k_colsum(const float* __restrict__ y, float* __restrict__ ksum,
                         float* __restrict__ ksum2) {
    int idx = blockIdx.x * 256 + threadIdx.x;
    if (idx >= HH * WW) return;
    float a = y[idx], b = y[idx + HH * WW], c = y[idx + 2 * HH * WW];
    ksum[idx]  = a + b + c;
    ksum2[idx] = a * a + b * b + c * c;
}

__global__ void k_hsum(const float* __restrict__ ksum, const float* __restrict__ ksum2,
                       float* __restrict__ h1, float* __restrict__ h2) {
    int idx = blockIdx.x * 256 + threadIdx.x;
    if (idx >= HH * WC) return;
    int h = idx / WC, w = idx % WC;
    const float* r  = ksum  + h * WW + w;
    const float* r2 = ksum2 + h * WW + w;
    float s = 0.f, s2 = 0.f;
    #pragma unroll
    for (int j = 0; j < KS; j++) { s += r[j]; s2 += r2[j]; }
    h1[idx] = s; h2[idx] = s2;
}

__global__ void k_vsum(const float* __restrict__ h1, const float* __restrict__ h2,
                       float* __restrict__ s1map, float* __restrict__ invd) {
    int idx = blockIdx.x * 256 + threadIdx.x;
    if (idx >= HC * WC) return;
    int r = idx / WC, w = idx % WC;
    float s = 0.f, s2 = 0.f;
    #pragma unroll
    for (int i = 0; i < KS; i++) { s += h1[(r + i) * WC + w]; s2 += h2[(r + i) * WC + w]; }
    s1map[idx] = s;
    float d2 = s2 - s * s * (1.0f / 576.0f);
    invd[idx] = rsqrtf(fmaxf(d2, 1e-20f));
}

__global__ void k_meanx(const float* __restrict__ x, float* __restrict__ mx) {
    int p = blockIdx.x;
    int pr = p >> 4, pc = p & 15;
    float s = 0.f;
    for (int e = threadIdx.x; e < CH * KS * KS; e += 256) {
        int c = e / (KS * KS); int rem = e % (KS * KS);
        int i = rem / KS, j = rem % KS;
        s += x[(c * XH + pr * KS + i) * XW + pc * KS + j];
    }
    __shared__ float red[256];
    red[threadIdx.x] = s; __syncthreads();
    for (int st = 128; st > 0; st >>= 1) {
        if (threadIdx.x < st) red[threadIdx.x] += red[threadIdx.x + st];
        __syncthreads();
    }
    if (threadIdx.x == 0) mx[p] = red[0] * (1.0f / 1728.0f);
}

// -------------------- B-matrix build: patches -> bf16, k=(c*24+i)*24+j --------------------

__global__ void k_bmat(const float* __restrict__ x, ushort_t* __restrict__ bm) {
    int p = blockIdx.x; int pr = p >> 4, pc = p & 15;
    for (int e = threadIdx.x; e < CH * KS * KS; e += 256) {
        int c = e / (KS * KS), rem = e % (KS * KS), i = rem / KS, j = rem % KS;
        float v = x[(c * XH + pr * KS + i) * XW + pc * KS + j];
        union { __bf16 h; ushort_t u; } cv; cv.h = (__bf16)v;
        bm[p * 1728 + e] = cv.u;
    }
}

// -------------------- main MFMA correlation kernel --------------------
// Implicit GEMM: A = sliding windows (128 positions/block), B = 256 patches, K=1728.
// Emits per-(patch, block) max of approx score.

__global__ __launch_bounds__(256, 2) void k_corr(
    const float* __restrict__ ydec, const ushort_t* __restrict__ bmat,
    const float* __restrict__ s1map, const float* __restrict__ invd,
    const float* __restrict__ mx, float* __restrict__ pscore)
{
    __shared__ ushort_t alds[128 * APITCH];   // 10240 B  A tile, bf16, pitch 80B
    __shared__ ushort_t blds[NP  * BPITCH];   // 20480 B  B tile, bf16
    __shared__ float    red[NP * 2];

    const int tid = threadIdx.x;
    const int bx = blockIdx.x % NBX, by = blockIdx.x / NBX;
    const int r0 = by * BROWS, w0 = bx * BCOLS;
    const bool edge = (bx == NBX - 1) || (by == NBY - 1);

    // A staging: thread -> (row m = tid>>1, 16-kk half = tid&1); 16 consecutive k = 2 j-octets
    const int am = tid >> 1, ah = tid & 1;
    const int amr = am >> 5, amw = am & 31;

    float areg[16];
    uint4 breg[4];

    auto loadA = [&](int s) {
        #pragma unroll
        for (int u = 0; u < 2; u++) {
            int O = s * 4 + ah * 2 + u;            // global j-octet index (216 total)
            int c = O / 72, rr = O % 72;
            int i = rr / 3, j0 = (rr % 3) * 8;
            int row = r0 + amr + i;
            int colb = w0 + amw + j0;
            if (!edge) {
                const float* p = ydec + (c * HH + row) * WW + colb;
                #pragma unroll
                for (int q = 0; q < 8; q++) areg[u * 8 + q] = p[q];
            } else {
                // clamped reads touch only B-zero... actually only masked-invalid positions; safe.
                int rowc = row < HH ? row : HH - 1;
                const float* p = ydec + (c * HH + rowc) * WW;
                #pragma unroll
                for (int q = 0; q < 8; q++) {
                    int cc = colb + q; cc = cc < WW ? cc : WW - 1;
                    areg[u * 8 + q] = p[cc];
                }
            }
        }
    };
    auto loadB = [&](int s) {
        const uint4* bp = (const uint4*)(bmat + tid * 1728 + s * 32);  // 16B-aligned
        #pragma unroll
        for (int k = 0; k < 4; k++) breg[k] = bp[k];
    };
    auto store = [&]() {
        bf16x8 v0, v1;
        #pragma unroll
        for (int q = 0; q < 8; q++) { v0[q] = (__bf16)areg[q]; v1[q] = (__bf16)areg[8 + q]; }
        int ao = am * APITCH + ah * 16;
        *(bf16x8*)(alds + ao)     = v0;
        *(bf16x8*)(alds + ao + 8) = v1;
        uint4* bo = (uint4*)(blds + tid * BPITCH);
        #pragma unroll
        for (int k = 0; k < 4; k++) bo[k] = breg[k];
    };

    const int lane = tid & 63, wave = tid >> 6;
    const int wm = wave >> 1, wn = wave & 1;    // wave tile: 64 m x 128 n
    const int l15 = lane & 15, quad = lane >> 4;

    v4f zero = {0.f, 0.f, 0.f, 0.f};
    v4f acc[4][8];
    #pragma unroll
    for (int a = 0; a < 4; a++)
        #pragma unroll
        for (int b = 0; b < 8; b++) acc[a][b] = zero;

    loadA(0); loadB(0);

    #pragma unroll 1
    for (int s = 0; s < NSTEP; s++) {
        __syncthreads();
        store();
        __syncthreads();
        if (s + 1 < NSTEP) { loadA(s + 1); loadB(s + 1); }
        bf16x8 af[4], bfg[8];
        #pragma unroll
        for (int mt = 0; mt < 4; mt++)
            af[mt] = *(const bf16x8*)(alds + (wm * 64 + mt * 16 + l15) * APITCH + quad * 8);
        #pragma unroll
        for (int nt = 0; nt < 8; nt++)
            bfg[nt] = *(const bf16x8*)(blds + (wn * 128 + nt * 16 + l15) * BPITCH + quad * 8);
        #pragma unroll
        for (int mt = 0; mt < 4; mt++)
            #pragma unroll
            for (int nt = 0; nt < 8; nt++)
                acc[mt][nt] = __builtin_amdgcn_mfma_f32_16x16x32_bf16(af[mt], bfg[nt], acc[mt][nt], 0, 0, 0);
    }

    // epilogue: approx score + per-(patch, block) max
    float mxv[8];
    #pragma unroll
    for (int nt = 0; nt < 8; nt++) mxv[nt] = mx[wn * 128 + nt * 16 + l15];

    float best[8];
    #pragma unroll
    for (int nt = 0; nt < 8; nt++) best[nt] = -1e30f;

    #pragma unroll
    for (int mt = 0; mt < 4; mt++) {
        #pragma unroll
        for (int r = 0; r < 4; r++) {
            int m = wm * 64 + mt * 16 + quad * 4 + r;   // C/D row = quad*4+reg (m89-verified)
            int mr = m >> 5, mw = m & 31;
            int rg = r0 + mr, wg = w0 + mw;
            bool valid = (rg < HC) && (wg < WC);
            int pos = rg * WC + wg;
            float S1 = 0.f, iv = 0.f;
            if (valid) { S1 = s1map[pos]; iv = invd[pos]; }
            #pragma unroll
            for (int nt = 0; nt < 8; nt++) {
                float sc = valid ? (acc[mt][nt][r] - mxv[nt] * S1) * iv : -1e30f;
                best[nt] = fmaxf(best[nt], sc);
            }
        }
    }
    #pragma unroll
    for (int nt = 0; nt < 8; nt++) {
        float b = best[nt];
        b = fmaxf(b, __shfl_xor(b, 16));
        b = fmaxf(b, __shfl_xor(b, 32));
        best[nt] = b;
    }
    if (lane < 16) {
        #pragma unroll
        for (int nt = 0; nt < 8; nt++) red[(wn * 128 + nt * 16 + l15) * 2 + wm] = best[nt];
    }
    __syncthreads();
    if (tid < NP) {
        float b = fmaxf(red[tid * 2], red[tid * 2 + 1]);
        pscore[tid * NBLK + blockIdx.x] = b;
    }
}

// -------------------- per-patch top-8 blocks --------------------

__global__ void k_select(const float* __restrict__ pscore, int* __restrict__ cand) {
    int p = blockIdx.x, tid = threadIdx.x;
    __shared__ float ls[NBLK];        // 17952 B
    __shared__ float rs[256];
    __shared__ int   ri[256];
    for (int e = tid; e < NBLK; e += 256) ls[e] = pscore[p * NBLK + e];
    __syncthreads();
    for (int round = 0; round < NCAND; round++) {
        float bs = -1e38f; int bi = 0;
        for (int e = tid; e < NBLK; e += 256) if (ls[e] > bs) { bs = ls[e]; bi = e; }
        rs[tid] = bs; ri[tid] = bi; __syncthreads();
        for (int st = 128; st > 0; st >>= 1) {
            if (tid < st && rs[tid + st] > rs[tid]) { rs[tid] = rs[tid + st]; ri[tid] = ri[tid + st]; }
            __syncthreads();
        }
        int win = ri[0];
        if (tid == 0) cand[p * NCAND + round] = win;
        if (tid == (win & 255)) ls[win] = -1e38f;
        __syncthreads();
    }
}

// -------------------- exact fp32 rescore of top-8 blocks + argmax + gather --------------------

__global__ void k_rescore(const int* __restrict__ cand, const float* __restrict__ xdec,
                          const float* __restrict__ ydec, const float* __restrict__ s1map,
                          const float* __restrict__ invd, const float* __restrict__ mx,
                          const float* __restrict__ yfull, float* __restrict__ out) {
    int p = blockIdx.x, tid = threadIdx.x;
    int pr = p >> 4, pc = p & 15;
    float mxp = mx[p];
    float best = -1e30f; int bpos = 0x7FFFFFFF;
    // 8 candidate blocks x 128 positions; 256 threads -> 2 threads rows of 4x32
    #pragma unroll 1
    for (int cdp = 0; cdp < 4; cdp++) {
        int cd = cdp * 2 + (tid >> 7);
        int blk = cand[p * NCAND + cd];
        int r0 = (blk / NBX) * BROWS, w0 = (blk % NBX) * BCOLS;
        int pi = tid & 127;
        int rg = r0 + (pi >> 5), wg = w0 + (pi & 31);
        if (rg < HC && wg < WC) {
            float sxy = 0.f;
            for (int c = 0; c < CH; c++) {
                #pragma unroll 1
                for (int i = 0; i < KS; i++) {
                    const float* yr = ydec + (c * HH + rg + i) * WW + wg;
                    const float* xr = xdec + (c * XH + pr * KS + i) * XW + pc * KS;
                    #pragma unroll
                    for (int j = 0; j < KS; j++) sxy = fmaf(yr[j], xr[j], sxy);
                }
            }
            int pos = rg * WC + wg;
            float sc = (sxy - mxp * s1map[pos]) * invd[pos];
            if (sc > best || (sc == best && pos < bpos)) { best = sc; bpos = pos; }
        }
    }
    __shared__ float rs[256];
    __shared__ int   ri[256];
    rs[tid] = best; ri[tid] = bpos; __syncthreads();
    for (int st = 128; st > 0; st >>= 1) {
        if (tid < st) {
            if (rs[tid + st] > rs[tid] || (rs[tid + st] == rs[tid] && ri[tid + st] < ri[tid])) {
                rs[tid] = rs[tid + st]; ri[tid] = ri[tid + st];
            }
        }
        __syncthreads();
    }
    int bestpos = ri[0];
    int row = bestpos / WC, col = bestpos % WC;
    for (int e = tid; e < CH * KS * KS; e += 256) {
        int c = e / (KS * KS), rem = e % (KS * KS), i = rem / KS, j = rem % KS;
        out[p * CH * KS * KS + e] = yfull[(c * HH + row + i) * WW + col + j];
    }
}

// -------------------- launch --------------------

extern "C" void kernel_launch(void* const* d_in, const int* in_sizes, int n_in,
                              void* d_out, int out_size, void* d_ws, size_t ws_size,
                              hipStream_t stream) {
    const float* xdec = (const float*)d_in[0];   // (1,3,384,384)
    const float* ydec = (const float*)d_in[1];   // (1,3,768,768)
    const float* y    = (const float*)d_in[2];   // (1,3,768,768)
    float* out = (float*)d_out;                  // (256,3,24,24)

    float* ws = (float*)d_ws;
    // phase-1 temps (consumed by k_vsum):
    float* ksum  = ws + 0;          // 589824
    float* ksum2 = ws + 589824;     // 589824
    float* h1    = ws + 1179648;    // 572160
    float* h2    = ws + 1751808;    // 572160
    // persistent:
    float* s1map = ws + 2323968;    // 555025
    float* invd  = ws + 2879040;    // 555025
    float* mx    = ws + 3434112;    // 256
    // phase-2 aliases over the (freed) box-sum region:
    ushort_t* Bmat = (ushort_t*)ws;                    // 256*1728 bf16 = 221184 floats
    float* pscore  = ws + 221184;                      // 256*4488 = 1148928
    int*   cand    = (int*)(ws + 221184 + 1148928);    // 256*8

    k_colsum<<<(HH * WW + 255) / 256, 256, 0, stream>>>(ydec, ksum, ksum2);
    k_hsum<<<(HH * WC + 255) / 256, 256, 0, stream>>>(ksum, ksum2, h1, h2);
    k_vsum<<<(HC * WC + 255) / 256, 256, 0, stream>>>(h1, h2, s1map, invd);
    k_meanx<<<NP, 256, 0, stream>>>(xdec, mx);
    k_bmat<<<NP, 256, 0, stream>>>(xdec, Bmat);        // overwrites ksum region (stream-ordered, safe)

    k_corr<<<NBLK, 256, 0, stream>>>(ydec, Bmat, s1map, invd, mx, pscore);
    k_select<<<NP, 256, 0, stream>>>(pscore, cand);
    k_rescore<<<NP, 256, 0, stream>>>(cand, xdec, ydec, s1map, invd, mx, y, out);
}

// Round 5
// 902.123 us; speedup vs baseline: 5.3536x; 2.0795x over previous
//
#include <hip/hip_runtime.h>

typedef __bf16 bf16x8 __attribute__((ext_vector_type(8)));
typedef float  v16f   __attribute__((ext_vector_type(16)));
typedef unsigned short ushort_t;

#define HH 768
#define WW 768
#define CH 3
#define KS 24
#define HC 745
#define WC 745
#define NP 256
#define XH 384
#define XW 384

#define NBX 24            // ceil(745/32)
#define NBY 187           // ceil(745/4)
#define NBLK (NBX*NBY)    // 4488
#define BROWS 4
#define BCOLS 32
#define NSTEP 54          // K=1728 in 32-wide slices
#define NCAND 8

// async global->LDS DMA; LDS dest = wave-uniform base + lane*size
__device__ __forceinline__ void gload16(const ushort_t* g, ushort_t* l) {
    __builtin_amdgcn_global_load_lds(
        (const __attribute__((address_space(1))) unsigned int*)(const void*)g,
        (__attribute__((address_space(3))) unsigned int*)(void*)l, 16, 0, 0);
}
__device__ __forceinline__ void gload4(const ushort_t* g, ushort_t* l) {
    __builtin_amdgcn_global_load_lds(
        (const __attribute__((address_space(1))) unsigned int*)(const void*)g,
        (__attribute__((address_space(3))) unsigned int*)(void*)l, 4, 0, 0);
}
__device__ __forceinline__ ushort_t f2bf(float f) {
    union { __bf16 h; ushort_t u; } cv; cv.h = (__bf16)f; return cv.u;
}
__device__ __forceinline__ float bf2f(ushort_t u) {
    union { unsigned u; float f; } cv; cv.u = ((unsigned)u) << 16; return cv.f;
}

// -------------------- prep kernels --------------------

__global__ void k_colsum(const float* __restrict__ y, float* __restrict__ ksum,
                         float* __restrict__ ksum2) {
    int idx = blockIdx.x * 256 + threadIdx.x;
    if (idx >= HH * WW) return;
    float a = y[idx], b = y[idx + HH * WW], c = y[idx + 2 * HH * WW];
    ksum[idx]  = a + b + c;
    ksum2[idx] = a * a + b * b + c * c;
}

__global__ void k_hsum(const float* __restrict__ ksum, const float* __restrict__ ksum2,
                       float* __restrict__ h1, float* __restrict__ h2) {
    int idx = blockIdx.x * 256 + threadIdx.x;
    if (idx >= HH * WC) return;
    int h = idx / WC, w = idx % WC;
    const float* r  = ksum  + h * WW + w;
    const float* r2 = ksum2 + h * WW + w;
    float s = 0.f, s2 = 0.f;
    #pragma unroll
    for (int j = 0; j < KS; j++) { s += r[j]; s2 += r2[j]; }
    h1[idx] = s; h2[idx] = s2;
}

// bf16 maps are ONLY used for the approximate pre-screen; k_rescore recomputes exactly.
__global__ void k_vsum(const float* __restrict__ h1, const float* __restrict__ h2,
                       ushort_t* __restrict__ s1m, ushort_t* __restrict__ ivm) {
    int idx = blockIdx.x * 256 + threadIdx.x;
    if (idx >= HC * WC) return;
    int r = idx / WC, w = idx % WC;
    float s = 0.f, s2 = 0.f;
    #pragma unroll
    for (int i = 0; i < KS; i++) { s += h1[(r + i) * WC + w]; s2 += h2[(r + i) * WC + w]; }
    float d2 = s2 - s * s * (1.0f / 576.0f);
    s1m[idx] = f2bf(s);
    ivm[idx] = f2bf(rsqrtf(fmaxf(d2, 1e-20f)));
}

__global__ void k_meanx(const float* __restrict__ x, float* __restrict__ mx) {
    int p = blockIdx.x;
    int pr = p >> 4, pc = p & 15;
    float s = 0.f;
    for (int e = threadIdx.x; e < CH * KS * KS; e += 256) {
        int c = e / (KS * KS); int rem = e % (KS * KS);
        int i = rem / KS, j = rem % KS;
        s += x[(c * XH + pr * KS + i) * XW + pc * KS + j];
    }
    __shared__ float red[256];
    red[threadIdx.x] = s; __syncthreads();
    for (int st = 128; st > 0; st >>= 1) {
        if (threadIdx.x < st) red[threadIdx.x] += red[threadIdx.x + st];
        __syncthreads();
    }
    if (threadIdx.x == 0) mx[p] = red[0] * (1.0f / 1728.0f);
}

__global__ void k_bmat(const float* __restrict__ x, ushort_t* __restrict__ bm) {
    int p = blockIdx.x; int pr = p >> 4, pc = p & 15;
    for (int e = threadIdx.x; e < CH * KS * KS; e += 256) {
        int c = e / (KS * KS), rem = e % (KS * KS), i = rem / KS, j = rem % KS;
        bm[p * 1728 + e] = f2bf(x[(c * XH + pr * KS + i) * XW + pc * KS + j]);
    }
}

// 2 column-shifted bf16 copies: y2[S][c][r][t] = bf16(ydec[c][r][t+S]), S in {0,1}, 0-pad OOB.
__global__ void k_y2(const float* __restrict__ yd, ushort_t* __restrict__ y2) {
    int idx = blockIdx.x * 256 + threadIdx.x;
    if (idx >= 2 * 3 * HH * (WW / 8)) return;
    int t8 = idx % (WW / 8); int rem = idx / (WW / 8);
    int r = rem % HH; rem /= HH;
    int c = rem % 3; int S = rem / 3;
    const float* src = yd + (c * HH + r) * WW;
    union { ushort_t u[8]; uint4 v; } o;
    #pragma unroll
    for (int q = 0; q < 8; q++) {
        int t = t8 * 8 + q + S;
        o.u[q] = f2bf(t < WW ? src[t] : 0.f);
    }
    ((uint4*)(y2 + ((size_t)(S * 3 + c) * HH + r) * WW))[t8] = o.v;
}

// -------------------- main MFMA correlation kernel --------------------
// 512 thr, tile = 128 pos (4x32) x 256 patches; wave tile 64x64 of mfma_f32_32x32x16_bf16.
// A staged via 4x gload4 from the parity-matched shifted copy (4B align guaranteed);
// B staged via 2x gload16 from the aligned patch matrix.

__global__ __launch_bounds__(512, 4) void k_corr(
    const ushort_t* __restrict__ y2, const ushort_t* __restrict__ bmat,
    const ushort_t* __restrict__ s1m, const ushort_t* __restrict__ ivm,
    const float* __restrict__ mx, ushort_t* __restrict__ ps16)
{
    __shared__ __align__(16) ushort_t Ab[128 * 32];   // 8KB  [pos][k0..31]
    __shared__ __align__(16) ushort_t Bb[256 * 32];   // 16KB [pat][k0..31]
    __shared__ float red[NP * 2];

    const int tid = threadIdx.x;
    const int wave = tid >> 6, lane = tid & 63;
    const int bx = blockIdx.x % NBX, by = blockIdx.x / NBX;
    const int r0 = by * BROWS, w0 = bx * BCOLS;

    // A staging: thread -> positions pos_u = u*32 + (tid>>4) (u=0..3 rows), k-pair dw = tid&15.
    // LDS dest check: (tid>>4)*64 + (tid&15)*4 == 4*tid == wave*256 + lane*4  (bytes).
    const int pcol = tid >> 4;           // position column offset 0..31 (fixed parity!)
    const int dw   = tid & 15;           // k-pair within 32-wide slice
    const int Sp   = pcol & 1;           // parity -> which shifted copy
    // pairid(s) = s*16 + dw; ci = pairid/12; jp = pairid%12; c = ci/24; i = ci%24
    int ci0 = (dw >= 12) ? 1 : 0;
    int jp  = dw - ci0 * 12;
    int c = 0, i = ci0;
    const ushort_t* abase_g = y2 + (size_t)(Sp * 3) * HH * WW + (size_t)r0 * WW + (w0 + pcol - Sp);
    ushort_t* alds  = Ab + wave * 128;            // +u*1024 ushorts per row-call
    const ushort_t* gb = bmat + (tid >> 2) * 1728 + (tid & 3) * 8;
    ushort_t* blds0 = Bb + wave * 512;
    ushort_t* blds1 = Bb + 4096 + wave * 512;

    const int l31 = lane & 31, h = lane >> 5;
    const int wm = wave >> 2, wn = wave & 3;

    v16f acc[2][2];
    #pragma unroll
    for (int a = 0; a < 2; a++)
        #pragma unroll
        for (int b = 0; b < 2; b++)
            #pragma unroll
            for (int r = 0; r < 16; r++) acc[a][b][r] = 0.f;

    #pragma unroll 1
    for (int s = 0; s < NSTEP; s++) {
        const ushort_t* ga  = abase_g + (c * HH + i) * WW + jp * 2;
        const ushort_t* gbs = gb + s * 32;
        __syncthreads();                       // old tiles fully consumed
        gload4(ga,            alds);           // row u=0
        gload4(ga + WW,       alds + 1024);    // u=1
        gload4(ga + 2 * WW,   alds + 2048);    // u=2
        gload4(ga + 3 * WW,   alds + 3072);    // u=3
        gload16(gbs,              blds0);
        gload16(gbs + 128 * 1728, blds1);
        __syncthreads();                       // staging landed (vmcnt drained at barrier)
        {   // advance (c,i,jp): pairid += 16 = 12 + 4
            jp += 4;
            int wrap = (jp >= 12) ? 1 : 0;
            if (wrap) jp -= 12;
            i += 1 + wrap;
            if (i >= KS) { i -= KS; c += 1; }
        }
        bf16x8 af[2][2], bfr[2][2];
        #pragma unroll
        for (int mt = 0; mt < 2; mt++)
            #pragma unroll
            for (int ks = 0; ks < 2; ks++)
                af[mt][ks] = *(const bf16x8*)(Ab + (wm * 64 + mt * 32 + l31) * 32 + (ks * 2 + h) * 8);
        #pragma unroll
        for (int nt = 0; nt < 2; nt++)
            #pragma unroll
            for (int ks = 0; ks < 2; ks++)
                bfr[nt][ks] = *(const bf16x8*)(Bb + (wn * 64 + nt * 32 + l31) * 32 + (ks * 2 + h) * 8);
        #pragma unroll
        for (int ks = 0; ks < 2; ks++)
            #pragma unroll
            for (int mt = 0; mt < 2; mt++)
                #pragma unroll
                for (int nt = 0; nt < 2; nt++)
                    acc[mt][nt] = __builtin_amdgcn_mfma_f32_32x32x16_bf16(
                        af[mt][ks], bfr[nt][ks], acc[mt][nt], 0, 0, 0);
    }

    // epilogue: approx score + per-(patch, block) max
    float mx0 = mx[wn * 64 + l31];
    float mx1 = mx[wn * 64 + 32 + l31];
    float best0 = -1e30f, best1 = -1e30f;
    #pragma unroll
    for (int mt = 0; mt < 2; mt++) {
        #pragma unroll
        for (int r = 0; r < 16; r++) {
            int row32 = (r & 3) + 8 * (r >> 2) + 4 * h;   // 32x32 C/D row (m74/m101)
            int posid = wm * 64 + mt * 32 + row32;
            int rg = r0 + (posid >> 5), wg = w0 + (posid & 31);
            bool valid = (rg < HC) && (wg < WC);
            int pos = rg * WC + wg;
            float S1 = valid ? bf2f(s1m[pos]) : 0.f;
            float iv = valid ? bf2f(ivm[pos]) : 0.f;
            float sc0 = valid ? (acc[mt][0][r] - mx0 * S1) * iv : -1e30f;
            float sc1 = valid ? (acc[mt][1][r] - mx1 * S1) * iv : -1e30f;
            best0 = fmaxf(best0, sc0);
            best1 = fmaxf(best1, sc1);
        }
    }
    best0 = fmaxf(best0, __shfl_xor(best0, 32));
    best1 = fmaxf(best1, __shfl_xor(best1, 32));
    __syncthreads();
    if (h == 0) {
        red[(wn * 64 + l31) * 2 + wm]      = best0;
        red[(wn * 64 + 32 + l31) * 2 + wm] = best1;
    }
    __syncthreads();
    if (tid < NP) ps16[blockIdx.x * NP + tid] = f2bf(fmaxf(red[tid * 2], red[tid * 2 + 1]));
}

// -------------------- per-patch top-8 blocks --------------------

__global__ void k_select(const ushort_t* __restrict__ ps16, int* __restrict__ cand) {
    int p = blockIdx.x, tid = threadIdx.x;
    __shared__ float ls[NBLK];
    __shared__ float rs[256];
    __shared__ int   ri[256];
    for (int e = tid; e < NBLK; e += 256) ls[e] = bf2f(ps16[e * NP + p]);
    __syncthreads();
    for (int round = 0; round < NCAND; round++) {
        float bs = -1e38f; int bi = 0;
        for (int e = tid; e < NBLK; e += 256) if (ls[e] > bs) { bs = ls[e]; bi = e; }
        rs[tid] = bs; ri[tid] = bi; __syncthreads();
        for (int st = 128; st > 0; st >>= 1) {
            if (tid < st && rs[tid + st] > rs[tid]) { rs[tid] = rs[tid + st]; ri[tid] = ri[tid + st]; }
            __syncthreads();
        }
        int win = ri[0];
        if (tid == 0) cand[p * NCAND + round] = win;
        if (tid == (win & 255)) ls[win] = -1e38f;
        __syncthreads();
    }
}

// -------------------- exact fp32 rescore (recomputes window sums) + gather --------------------

__global__ void k_rescore(const int* __restrict__ cand, const float* __restrict__ xdec,
                          const float* __restrict__ ydec, const float* __restrict__ mx,
                          const float* __restrict__ yfull, float* __restrict__ out) {
    int p = blockIdx.x, tid = threadIdx.x;
    int pr = p >> 4, pc = p & 15;
    float mxp = mx[p];
    float best = -1e30f; int bpos = 0x7FFFFFFF;
    #pragma unroll 1
    for (int cdp = 0; cdp < 4; cdp++) {
        int cd = cdp * 2 + (tid >> 7);
        int blk = cand[p * NCAND + cd];
        int r0 = (blk / NBX) * BROWS, w0 = (blk % NBX) * BCOLS;
        int pi = tid & 127;
        int rg = r0 + (pi >> 5), wg = w0 + (pi & 31);
        if (rg < HC && wg < WC) {
            float sxy = 0.f, sy = 0.f, sy2 = 0.f;
            for (int c = 0; c < CH; c++) {
                #pragma unroll 1
                for (int i = 0; i < KS; i++) {
                    const float* yr = ydec + (c * HH + rg + i) * WW + wg;
                    const float* xr = xdec + (c * XH + pr * KS + i) * XW + pc * KS;
                    #pragma unroll
                    for (int j = 0; j < KS; j++) {
                        float yv = yr[j];
                        sxy = fmaf(yv, xr[j], sxy);
                        sy += yv;
                        sy2 = fmaf(yv, yv, sy2);
                    }
                }
            }
            float d2 = sy2 - sy * sy * (1.0f / 576.0f);
            int pos = rg * WC + wg;
            float sc = (sxy - mxp * sy) * rsqrtf(fmaxf(d2, 1e-20f));
            if (sc > best || (sc == best && pos < bpos)) { best = sc; bpos = pos; }
        }
    }
    __shared__ float rs[256];
    __shared__ int   ri[256];
    rs[tid] = best; ri[tid] = bpos; __syncthreads();
    for (int st = 128; st > 0; st >>= 1) {
        if (tid < st) {
            if (rs[tid + st] > rs[tid] || (rs[tid + st] == rs[tid] && ri[tid + st] < ri[tid])) {
                rs[tid] = rs[tid + st]; ri[tid] = ri[tid + st];
            }
        }
        __syncthreads();
    }
    int bestpos = ri[0];
    int row = bestpos / WC, col = bestpos % WC;
    for (int e = tid; e < CH * KS * KS; e += 256) {
        int c = e / (KS * KS), rem = e % (KS * KS), i = rem / KS, j = rem % KS;
        out[p * CH * KS * KS + e] = yfull[(c * HH + row + i) * WW + col + j];
    }
}

// -------------------- launch --------------------
// Total ws: 3,124,512 floats = 11.9 MB (R1-R3's proven footprint was 13.7 MB; R4's 37.8 MB
// is the prime suspect for its failure).

extern "C" void kernel_launch(void* const* d_in, const int* in_sizes, int n_in,
                              void* d_out, int out_size, void* d_ws, size_t ws_size,
                              hipStream_t stream) {
    const float* xdec = (const float*)d_in[0];   // (1,3,384,384)
    const float* ydec = (const float*)d_in[1];   // (1,3,768,768)
    const float* y    = (const float*)d_in[2];   // (1,3,768,768)
    float* out = (float*)d_out;                  // (256,3,24,24)

    float* ws = (float*)d_ws;
    ushort_t* s1m16 = (ushort_t*)(ws + 0);         // 555025 u16 (pad to 277520 floats)
    ushort_t* ivm16 = (ushort_t*)(ws + 277520);    // 555025 u16
    float*    mx    = ws + 555040;                 // 256
    ushort_t* Bmat  = (ushort_t*)(ws + 555296);    // 442368 u16 (16B-aligned: 555296*4 % 16 == 0)
    int*      cand  = (int*)(ws + 776480);         // 2048
    ushort_t* ps16  = (ushort_t*)(ws + 778528);    // 1,148,928 u16 [blk][pat]
    ushort_t* y2    = (ushort_t*)(ws + 1352992);   // 3,538,944 u16 + 4096 pad (16B-aligned)
    // box-sum temps alias ps16+y2 region (dead before k_y2/k_corr):
    float* ksum  = ws + 778528;                    // 589824
    float* ksum2 = ws + 1368352;                   // 589824
    float* h1    = ws + 1958176;                   // 572160
    float* h2    = ws + 2530336;                   // 572160 (end 3,102,496 < 3,124,512)

    k_colsum<<<(HH * WW + 255) / 256, 256, 0, stream>>>(ydec, ksum, ksum2);
    k_hsum<<<(HH * WC + 255) / 256, 256, 0, stream>>>(ksum, ksum2, h1, h2);
    k_vsum<<<(HC * WC + 255) / 256, 256, 0, stream>>>(h1, h2, s1m16, ivm16);
    k_meanx<<<NP, 256, 0, stream>>>(xdec, mx);
    k_bmat<<<NP, 256, 0, stream>>>(xdec, Bmat);
    k_y2<<<(2 * 3 * HH * (WW / 8) + 255) / 256, 256, 0, stream>>>(ydec, y2);

    k_corr<<<NBLK, 512, 0, stream>>>(y2, Bmat, s1m16, ivm16, mx, ps16);
    k_select<<<NP, 256, 0, stream>>>(ps16, cand);
    k_rescore<<<NP, 256, 0, stream>>>(cand, xdec, ydec, mx, y, out);
}